// Round 6
// baseline (78.010 us; speedup 1.0000x reference)
//
#include <hip/hip_runtime.h>
#include <math.h>

// L=13, M=12, ODD_KS=(1,3,5) -> NK=3
#define LL    13
#define MM    12
#define NKK   3
#define BLOCK 256                 // threads
#define RPT   2                   // outputs per thread (consecutive t)
#define TILE  (BLOCK * RPT)       // 512 outputs per block
#define HALO  24                  // window spans [t-24, t+24]
#define WIN   (TILE + 2 * HALO)   // 560 samples staged

// LDS map (window base t0-24), i0 = 2*tid (tile-local pos of output 0):
//   out i: B-powers P[i+d], C-powers P[i+d+24], d in [0,24)
//          A-power  P[i+12+l] == p(d=l+12) for l<12, == q(d=0) for l=12
//          x1(l)=Z[i+l+12], x3last(l)=Z[i+l+36]
// Rolling regs: pA=P[i0+d], pB=P[i0+d+1], qA=P[i0+d+24], qB=P[i0+d+25]
// give both outputs' powers with 2 new ds_read_b128 per d.

__global__ __launch_bounds__(BLOCK)
void gmp_kernel(const float* __restrict__ x,    // (B,T,2)
                const float* __restrict__ Ac,   // (L,NK)
                const float* __restrict__ Bc,   // (L,M,NK)
                const float* __restrict__ Cc,   // (L,M,NK)
                float* __restrict__ out,        // (B,T,2)
                int T, int tilesPerB)
{
    __shared__ float4 sP[WIN];   // {a, a^3, a^5, 0}
    __shared__ float2 sZ[WIN];   // {re, im}

    const int tid = threadIdx.x;
    const int i0  = 2 * tid;
    const int b   = blockIdx.x / tilesPerB;
    const int t0  = (blockIdx.x % tilesPerB) * TILE;

    const float* xb = x + (size_t)b * T * 2;

    // Stage 560-sample window (circular wrap); powers once per sample
    for (int j = tid; j < WIN; j += BLOCK) {
        int t = t0 - HALO + j;
        if (t < 0)  t += T;
        if (t >= T) t -= T;
        const float2 z = *(const float2*)(xb + 2 * t);
        float a2 = z.x * z.x + z.y * z.y;
        float a  = sqrtf(a2);
        sZ[j] = z;
        sP[j] = make_float4(a, a * a2, a * a2 * a2, 0.0f);
    }
    __syncthreads();

    float cB0[LL], cC0[LL], cB1[LL], cC1[LL];
    #pragma unroll
    for (int l = 0; l < LL; ++l) { cB0[l] = cC0[l] = cB1[l] = cC1[l] = 0.0f; }

    float4 pA = sP[i0];
    float4 qA = sP[i0 + HALO];

    #pragma unroll
    for (int d = 0; d < LL + MM - 1; ++d) {         // 24 iterations
        const float4 pB = sP[i0 + d + 1];
        const float4 qB = sP[i0 + d + HALO + 1];

        if (d == 0) {                               // A-term, l = 12
            const float* ap = Ac + 12 * NKK;
            cB0[12] += ap[0] * qA.x + ap[1] * qA.y + ap[2] * qA.z;
            cB1[12] += ap[0] * qB.x + ap[1] * qB.y + ap[2] * qB.z;
        }
        if (d >= 12) {                              // A-term, l = d-12 in [0,12)
            const int l = d - 12;
            const float* ap = Ac + l * NKK;
            cB0[l] += ap[0] * pA.x + ap[1] * pA.y + ap[2] * pA.z;
            cB1[l] += ap[0] * pB.x + ap[1] * pB.y + ap[2] * pB.z;
        }

        #pragma unroll
        for (int l = 0; l < LL; ++l) {
            const int m = d - l;
            if (m >= 0 && m < MM) {                 // folds at compile time
                const float* bp = Bc + (l * MM + m) * NKK;
                cB0[l] += bp[0] * pA.x + bp[1] * pA.y + bp[2] * pA.z;
                cB1[l] += bp[0] * pB.x + bp[1] * pB.y + bp[2] * pB.z;
                const float* cp = Cc + (l * MM + m) * NKK;
                cC0[l] += cp[0] * qA.x + cp[1] * qA.y + cp[2] * qA.z;
                cC1[l] += cp[0] * qB.x + cp[1] * qB.y + cp[2] * qB.z;
            }
        }
        pA = pB;                                    // roll
        qA = qB;
    }

    // Epilogue with rolling Z reads:
    //   out0: z1=Z[i0+l+12], z3=Z[i0+l+36]; out1 uses the +1 neighbors.
    float sr0 = 0.f, si0 = 0.f, sr1 = 0.f, si1 = 0.f;
    float2 z1A = sZ[i0 + 12];
    float2 z3A = sZ[i0 + 36];
    #pragma unroll
    for (int l = 0; l < LL; ++l) {
        const float2 z1B = sZ[i0 + l + 13];
        const float2 z3B = sZ[i0 + l + 37];
        sr0 += z1A.x * cB0[l] + z3A.x * cC0[l];
        si0 += z1A.y * cB0[l] + z3A.y * cC0[l];
        sr1 += z1B.x * cB1[l] + z3B.x * cC1[l];
        si1 += z1B.y * cB1[l] + z3B.y * cC1[l];
        z1A = z1B;
        z3A = z3B;
    }

    const int t = t0 + i0;
    if (t + 1 < T) {
        // two adjacent complex outputs -> one 16B coalesced store
        float4* op = (float4*)(out + ((size_t)b * T + t) * 2);
        *op = make_float4(sr0, si0, sr1, si1);
    }
}

extern "C" void kernel_launch(void* const* d_in, const int* in_sizes, int n_in,
                              void* d_out, int out_size, void* d_ws, size_t ws_size,
                              hipStream_t stream)
{
    // Inputs: x (B,T,2) f32, h_0 (B,16) f32 [unused], A_kl (L,NK),
    // B_klm (L,M,NK), C_klm (L,M,NK)
    const float* x  = (const float*)d_in[0];
    const float* Ac = (const float*)d_in[2];
    const float* Bc = (const float*)d_in[3];
    const float* Cc = (const float*)d_in[4];
    float* out = (float*)d_out;

    const int Bsz = in_sizes[1] / 16;               // h_0 is (B,16)
    const int T   = in_sizes[0] / (2 * Bsz);        // x is (B,T,2)
    const int tilesPerB = (T + TILE - 1) / TILE;    // 16 for T=8192

    dim3 grid(Bsz * tilesPerB);                     // 256 blocks
    dim3 block(BLOCK);
    gmp_kernel<<<grid, block, 0, stream>>>(x, Ac, Bc, Cc, out, T, tilesPerB);
}